// Round 3
// baseline (121.536 us; speedup 1.0000x reference)
//
#include <hip/hip_runtime.h>

typedef unsigned short us;
typedef __attribute__((ext_vector_type(8))) short short8;
typedef __attribute__((ext_vector_type(4))) float f32x4;

__device__ __forceinline__ us f2bf(float f) {
  unsigned int u = __builtin_bit_cast(unsigned int, f);
  u += 0x7fffu + ((u >> 16) & 1u);
  return (us)(u >> 16);
}

// 16B-wide async global->LDS DMA. LDS dest = wave-uniform base + lane*16.
__device__ __forceinline__ void gload_lds16(const void* g, void* l) {
  __builtin_amdgcn_global_load_lds(
      (const __attribute__((address_space(1))) void*)g,
      (__attribute__((address_space(3))) void*)l, 16, 0, 0);
}

// ---- prep: entity k-split GEMM (256, first: overlaps latency with cast BW)
//           + token cast (4096) + Wt transpose (256) + cnt zero ----
__global__ __launch_bounds__(256) void prep_kernel(
    const float* __restrict__ token, us* __restrict__ tokb,
    const float* __restrict__ Wt, us* __restrict__ WtT,
    const float* __restrict__ entity, const float* __restrict__ We,
    float* __restrict__ epart, int* __restrict__ cnt) {
  __shared__ float tile[64][65];
  __shared__ float eS[16][128];
  const int bid = blockIdx.x, tid = threadIdx.x;
  if (bid < 256) {  // entity k-split partial GEMM, coalesced We reads
    if (bid == 0 && tid < 64) cnt[tid] = 0;  // re-zero every launch (ws poisoned)
    int kc = bid & 7, nt = (bid >> 3) & 7, b = bid >> 6;
    int k0 = kc << 7, n0 = nt << 7;
#pragma unroll
    for (int p = 0; p < 2; ++p) {
      int idx = (p << 8) + tid;
      int r = idx >> 5, kk = (idx & 31) << 2;
      *(float4*)&eS[r][kk] = *(const float4*)&entity[(size_t)(((b << 4) + r) << 10) + k0 + kk];
    }
    __syncthreads();
    const int col = tid & 127, rh = tid >> 7;
    const float* wP = We + ((size_t)k0 << 10) + n0 + col;
    float acc[8] = {0.f, 0.f, 0.f, 0.f, 0.f, 0.f, 0.f, 0.f};
#pragma unroll 8
    for (int k = 0; k < 128; ++k) {
      float wv = wP[(size_t)k << 10];
#pragma unroll
      for (int r = 0; r < 8; ++r)
        acc[r] = fmaf(wv, eS[(rh << 3) + r][k], acc[r]);
    }
    float* op = epart + (((size_t)((kc << 6) + (b << 4) + (rh << 3))) << 10) + n0 + col;
#pragma unroll
    for (int r = 0; r < 8; ++r) op[(size_t)r << 10] = acc[r];
  } else if (bid < 4352) {  // token f32 -> bf16
    int q = (bid - 256) * 256 + tid;
    float4 v = ((const float4*)token)[q];
    ushort4 o;
    o.x = f2bf(v.x); o.y = f2bf(v.y); o.z = f2bf(v.z); o.w = f2bf(v.w);
    ((ushort4*)tokb)[q] = o;
  } else {  // Wt[k][n] -> WtT[n][k] bf16
    int tb = bid - 4352;
    int bx = (tb & 15) << 6, by = ((tb >> 4) & 15) << 6;
    int r0 = tid >> 4, c0 = (tid & 15) << 2;
#pragma unroll
    for (int p = 0; p < 4; ++p) {
      int r = p * 16 + r0;
      float4 v = *(const float4*)&Wt[(size_t)(by + r) * 1024 + bx + c0];
      tile[r][c0] = v.x; tile[r][c0 + 1] = v.y;
      tile[r][c0 + 2] = v.z; tile[r][c0 + 3] = v.w;
    }
    __syncthreads();
#pragma unroll
    for (int p = 0; p < 4; ++p) {
      int r = p * 16 + r0;
      ushort4 o;
      o.x = f2bf(tile[c0 + 0][r]); o.y = f2bf(tile[c0 + 1][r]);
      o.z = f2bf(tile[c0 + 2][r]); o.w = f2bf(tile[c0 + 3][r]);
      *(ushort4*)&WtT[(size_t)(bx + r) * 1024 + by + c0] = o;
    }
  }
}

// ---- main: transposed token GEMM (C[h,t]) + fused relu-dot epilogue
//      + R2: fused finalize via per-tt completion counter (last of 8 mh
//      blocks acquires and finalizes its 1024 outputs; XCD-coherence via
//      agent-scope release/acquire fences per Guideline 16) ----
// Tile 128h x 64t, grid (8 mh, 64 tt) = 512 blocks = 2/CU.
// K-step 64, both-sides XOR swizzle, counted vmcnt(6) never drained.
__global__ __launch_bounds__(256) void main_kernel(
    const us* __restrict__ tokb, const us* __restrict__ WtT,
    const float* __restrict__ epart, const float* __restrict__ be,
    const float* __restrict__ bt, const float* __restrict__ wp,
    float* __restrict__ partial, int* __restrict__ cnt,
    const float* __restrict__ bp, const int* __restrict__ mask,
    float* __restrict__ out) {
  __shared__ __attribute__((aligned(16))) us Ws[2][8192];  // 128h x 64k per buf (swizzled)
  __shared__ __attribute__((aligned(16))) us Ts[2][4096];  // 64t x 64k per buf (swizzled)
  __shared__ __attribute__((aligned(16))) float eL[16][132];
  __shared__ __attribute__((aligned(16))) float btL[128];
  __shared__ __attribute__((aligned(16))) float wpL[128];
  __shared__ float pp[2][64][17];
  __shared__ int oldS;
  const int tid = threadIdx.x;
  const int mh = blockIdx.x, tt = blockIdx.y;
  const int h0 = mh << 7, b = tt >> 4, t0 = (tt & 15) << 6;
  // phase 1: entity act = sum of 8 k-partials + be -> eL; bt, wp -> LDS
#pragma unroll
  for (int p = 0; p < 2; ++p) {
    int q = (p << 8) + tid;
    int er = q >> 5, ec = (q & 31) << 2;
    f32x4 s = *(const f32x4*)&be[h0 + ec];
#pragma unroll
    for (int kc = 0; kc < 8; ++kc)
      s += *(const f32x4*)&epart[(((size_t)((kc << 6) + (b << 4) + er)) << 10) + h0 + ec];
    *(f32x4*)&eL[er][ec] = s;
  }
  if (tid < 128) btL[tid] = bt[h0 + tid];
  else wpL[tid - 128] = wp[h0 + tid - 128];
  asm volatile("" ::: "memory");
  // staging geometry: chunk = 8 rows x 64k bf16 = 1KB = one gload_lds16/wave.
  // Per wave per k-tile: 4 Ws chunks (32 h-rows) + 2 Ts chunks (16 t-rows).
  const int w = tid >> 6, lane = tid & 63;
  const int lr = lane >> 3, lc = lane & 7;
  const int swz = ((lc ^ lr) << 3);  // inverse-swizzled k-element offset (const/lane)
  const us* wPs = WtT + (size_t)(h0 + (w << 5) + lr) * 1024 + swz;
  const us* tPs = tokb + (size_t)((b << 10) + t0 + (w << 4) + lr) * 1024 + swz;
  us* wD0 = &Ws[0][(w << 5) << 6];  // w*32 rows * 64 us
  us* wD1 = &Ws[1][(w << 5) << 6];
  us* tD0 = &Ts[0][(w << 4) << 6];  // w*16 rows * 64 us
  us* tD1 = &Ts[1][(w << 4) << 6];
  auto stage = [&](int kt, us* wD, us* tD) {
    const us* ws = wPs + (kt << 6);
    gload_lds16(ws,             wD);
    gload_lds16(ws + 8 * 1024,  wD + 512);
    gload_lds16(ws + 16 * 1024, wD + 1024);
    gload_lds16(ws + 24 * 1024, wD + 1536);
    const us* ts = tPs + (kt << 6);
    gload_lds16(ts,            tD);
    gload_lds16(ts + 8 * 1024, tD + 512);
  };
  // prologue: tile0 -> buf0, tile1 -> buf1 (12 outstanding, 6/tile)
  stage(0, wD0, tD0);
  stage(1, wD1, tD1);
  const int l16 = lane & 15, wm = (tid >> 7) & 1, wn = (tid >> 6) & 1, oct = lane >> 4;
  // swizzled fragment byte offsets: row*128 + ((kh*4+oct) ^ (row&7))*16
  int wfo[2][4], tfo[2][2];
#pragma unroll
  for (int kh = 0; kh < 2; ++kh)
#pragma unroll
    for (int i = 0; i < 4; ++i) {
      int row = (wm << 6) + (i << 4) + l16;
      wfo[kh][i] = (row << 7) + (((((kh << 2) + oct)) ^ (row & 7)) << 4);
    }
#pragma unroll
  for (int kh = 0; kh < 2; ++kh)
#pragma unroll
    for (int j = 0; j < 2; ++j) {
      int row = (wn << 5) + (j << 4) + l16;
      tfo[kh][j] = (row << 7) + (((((kh << 2) + oct)) ^ (row & 7)) << 4);
    }
  f32x4 acc[4][2] = {};
  for (int kt = 0; kt < 16; ++kt) {
    const char* Wb = (const char*)Ws[kt & 1];
    const char* Tb = (const char*)Ts[kt & 1];
    __builtin_amdgcn_s_waitcnt(0x0f76);  // vmcnt(6): oldest tile (6 loads) landed
    __builtin_amdgcn_s_barrier();
    asm volatile("" ::: "memory");
    short8 af[2][4], bfr[2][2];
#pragma unroll
    for (int kh = 0; kh < 2; ++kh)
#pragma unroll
      for (int i = 0; i < 4; ++i) af[kh][i] = *(const short8*)(Wb + wfo[kh][i]);
#pragma unroll
    for (int kh = 0; kh < 2; ++kh)
#pragma unroll
      for (int j = 0; j < 2; ++j) bfr[kh][j] = *(const short8*)(Tb + tfo[kh][j]);
#pragma unroll
    for (int i = 0; i < 4; ++i)
#pragma unroll
      for (int j = 0; j < 2; ++j)
        acc[i][j] = __builtin_amdgcn_mfma_f32_16x16x32_bf16(af[0][i], bfr[0][j], acc[i][j], 0, 0, 0);
#pragma unroll
    for (int i = 0; i < 4; ++i)
#pragma unroll
      for (int j = 0; j < 2; ++j)
        acc[i][j] = __builtin_amdgcn_mfma_f32_16x16x32_bf16(af[1][i], bfr[1][j], acc[i][j], 0, 0, 0);
    asm volatile("" ::: "memory");
    __builtin_amdgcn_s_barrier();
    // prefetch tile kt+2 into buf kt&1 (clamped dummy for last two iters)
    int nk = kt + 2; if (nk > 15) nk = 14;
    if (kt & 1) stage(nk, wD1, tD1); else stage(nk, wD0, tD0);
  }
  // ---- fused epilogue: per e, p[t] = sum_h relu(acc + bt + e) * Wp ----
  f32x4 btq[4], wpq[4];
#pragma unroll
  for (int i = 0; i < 4; ++i) {
    int hb = (wm << 6) + (i << 4) + (oct << 2);
    btq[i] = *(const f32x4*)&btL[hb];
    wpq[i] = *(const f32x4*)&wpL[hb];
  }
#pragma unroll
  for (int i = 0; i < 4; ++i)
#pragma unroll
    for (int j = 0; j < 2; ++j) acc[i][j] += btq[i];
#pragma unroll
  for (int e = 0; e < 16; ++e) {
    f32x4 ev[4];
#pragma unroll
    for (int i = 0; i < 4; ++i)
      ev[i] = *(const f32x4*)&eL[e][(wm << 6) + (i << 4) + (oct << 2)];
    float pj[2] = {0.f, 0.f};
#pragma unroll
    for (int j = 0; j < 2; ++j)
#pragma unroll
      for (int i = 0; i < 4; ++i)
#pragma unroll
        for (int r = 0; r < 4; ++r)
          pj[j] = fmaf(fmaxf(acc[i][j][r] + ev[i][r], 0.f), wpq[i][r], pj[j]);
#pragma unroll
    for (int j = 0; j < 2; ++j) {
      pj[j] += __shfl_xor(pj[j], 16, 64);
      pj[j] += __shfl_xor(pj[j], 32, 64);
    }
    if (oct == 0) {
#pragma unroll
      for (int j = 0; j < 2; ++j) pp[wm][(wn << 5) + (j << 4) + l16][e] = pj[j];
    }
  }
  __syncthreads();
#pragma unroll
  for (int q = 0; q < 4; ++q) {
    int flat = (q << 8) + tid;          // 0..1023 = e*64 + tl
    int e = flat >> 6, tl = flat & 63;
    float v = pp[0][tl][e] + pp[1][tl][e];
    partial[((size_t)mh << 16) + (size_t)((((b << 4) + e) << 10) + t0 + tl)] = v;
  }
  // ---- fused finalize: last of the 8 mh blocks for this tt reduces ----
  __syncthreads();  // drains partial stores (vmcnt 0) before fence
  if (tid == 0) {
    __builtin_amdgcn_fence(__ATOMIC_RELEASE, "agent");  // L2 writeback
    int old = atomicAdd(&cnt[tt], 1);
    if (old == 7) __builtin_amdgcn_fence(__ATOMIC_ACQUIRE, "agent");  // L1/L2 inv
    oldS = old;
  }
  __syncthreads();
  if (oldS == 7) {
    const float bp0 = bp[0];
#pragma unroll
    for (int q = 0; q < 4; ++q) {
      int flat = (q << 8) + tid;  // e*64 + tl
      int e = flat >> 6, tl = flat & 63;
      size_t idx = ((size_t)(((b << 4) + e) << 10)) + t0 + tl;
      float s = 0.f;
#pragma unroll
      for (int m2 = 0; m2 < 8; ++m2) s += partial[((size_t)m2 << 16) + idx];
      float cls = s + bp0;
      if (mask[(b << 10) + t0 + tl] == 0) cls = -10000.0f;
      out[idx] = cls;
      out[65536 + idx] = 1.0f / (1.0f + __expf(-cls));
    }
  }
}

extern "C" void kernel_launch(void* const* d_in, const int* in_sizes, int n_in,
                              void* d_out, int out_size, void* d_ws, size_t ws_size,
                              hipStream_t stream) {
  const float* token = (const float*)d_in[0];
  const float* entity = (const float*)d_in[1];
  const int* mask = (const int*)d_in[2];
  const float* Wt = (const float*)d_in[3];
  const float* bt = (const float*)d_in[4];
  const float* We = (const float*)d_in[5];
  const float* be = (const float*)d_in[6];
  const float* Wp = (const float*)d_in[7];
  const float* bp = (const float*)d_in[8];
  float* out = (float*)d_out;

  char* ws = (char*)d_ws;
  us* tokb = (us*)ws;                                   // 8 MB
  us* WtT = tokb + (size_t)4096 * 1024;                 // 2 MB
  float* epart = (float*)(WtT + (size_t)1024 * 1024);   // 2 MB [8][64][1024]
  float* partial = epart + (size_t)8 * 64 * 1024;       // 2 MB [8][4*16*1024]
  int* cnt = (int*)(partial + (size_t)8 * 64 * 1024);   // 64 x int

  prep_kernel<<<4608, 256, 0, stream>>>(token, tokb, Wt, WtT, entity, We, epart, cnt);
  main_kernel<<<dim3(8, 64), 256, 0, stream>>>(tokb, WtT, epart, be, bt, Wp,
                                               partial, cnt, bp, mask, out);
}

// Round 4
// 110.309 us; speedup vs baseline: 1.1018x; 1.1018x over previous
//
#include <hip/hip_runtime.h>

typedef unsigned short us;
typedef __attribute__((ext_vector_type(8))) short short8;
typedef __attribute__((ext_vector_type(4))) float f32x4;

__device__ __forceinline__ us f2bf(float f) {
  unsigned int u = __builtin_bit_cast(unsigned int, f);
  u += 0x7fffu + ((u >> 16) & 1u);
  return (us)(u >> 16);
}

// 16B-wide async global->LDS DMA. LDS dest = wave-uniform base + lane*16.
__device__ __forceinline__ void gload_lds16(const void* g, void* l) {
  __builtin_amdgcn_global_load_lds(
      (const __attribute__((address_space(1))) void*)g,
      (__attribute__((address_space(3))) void*)l, 16, 0, 0);
}

// ---- prep: entity k-split GEMM (256, first: overlaps latency with cast BW)
//           + token cast (4096) + Wt transpose (256) ----
__global__ __launch_bounds__(256) void prep_kernel(
    const float* __restrict__ token, us* __restrict__ tokb,
    const float* __restrict__ Wt, us* __restrict__ WtT,
    const float* __restrict__ entity, const float* __restrict__ We,
    float* __restrict__ epart) {
  __shared__ float tile[64][65];
  __shared__ float eS[16][128];
  const int bid = blockIdx.x, tid = threadIdx.x;
  if (bid < 256) {  // entity k-split partial GEMM, coalesced We reads
    int kc = bid & 7, nt = (bid >> 3) & 7, b = bid >> 6;
    int k0 = kc << 7, n0 = nt << 7;
#pragma unroll
    for (int p = 0; p < 2; ++p) {
      int idx = (p << 8) + tid;
      int r = idx >> 5, kk = (idx & 31) << 2;
      *(float4*)&eS[r][kk] = *(const float4*)&entity[(size_t)(((b << 4) + r) << 10) + k0 + kk];
    }
    __syncthreads();
    const int col = tid & 127, rh = tid >> 7;
    const float* wP = We + ((size_t)k0 << 10) + n0 + col;
    float acc[8] = {0.f, 0.f, 0.f, 0.f, 0.f, 0.f, 0.f, 0.f};
#pragma unroll 8
    for (int k = 0; k < 128; ++k) {
      float wv = wP[(size_t)k << 10];
#pragma unroll
      for (int r = 0; r < 8; ++r)
        acc[r] = fmaf(wv, eS[(rh << 3) + r][k], acc[r]);
    }
    float* op = epart + (((size_t)((kc << 6) + (b << 4) + (rh << 3))) << 10) + n0 + col;
#pragma unroll
    for (int r = 0; r < 8; ++r) op[(size_t)r << 10] = acc[r];
  } else if (bid < 4352) {  // token f32 -> bf16
    int q = (bid - 256) * 256 + tid;
    float4 v = ((const float4*)token)[q];
    ushort4 o;
    o.x = f2bf(v.x); o.y = f2bf(v.y); o.z = f2bf(v.z); o.w = f2bf(v.w);
    ((ushort4*)tokb)[q] = o;
  } else {  // Wt[k][n] -> WtT[n][k] bf16
    int tb = bid - 4352;
    int bx = (tb & 15) << 6, by = ((tb >> 4) & 15) << 6;
    int r0 = tid >> 4, c0 = (tid & 15) << 2;
#pragma unroll
    for (int p = 0; p < 4; ++p) {
      int r = p * 16 + r0;
      float4 v = *(const float4*)&Wt[(size_t)(by + r) * 1024 + bx + c0];
      tile[r][c0] = v.x; tile[r][c0 + 1] = v.y;
      tile[r][c0 + 2] = v.z; tile[r][c0 + 3] = v.w;
    }
    __syncthreads();
#pragma unroll
    for (int p = 0; p < 4; ++p) {
      int r = p * 16 + r0;
      ushort4 o;
      o.x = f2bf(tile[c0 + 0][r]); o.y = f2bf(tile[c0 + 1][r]);
      o.z = f2bf(tile[c0 + 2][r]); o.w = f2bf(tile[c0 + 3][r]);
      *(ushort4*)&WtT[(size_t)(bx + r) * 1024 + by + c0] = o;
    }
  }
}

// ---- main: transposed token GEMM (C[h,t]) + fused relu-dot epilogue ----
// Tile 128h x 64t, grid (8 mh, 64 tt) = 512 blocks = 2/CU.
// K-step 64 (16 iters), LDS rows 128B with XOR row-swizzle on BOTH sides:
// linear LDS dest + inverse-swizzled per-lane global source + swizzled
// ds_read offsets. Depth-2 pipeline: counted s_waitcnt vmcnt(6), never drained.
__global__ __launch_bounds__(256) void main_kernel(
    const us* __restrict__ tokb, const us* __restrict__ WtT,
    const float* __restrict__ epart, const float* __restrict__ be,
    const float* __restrict__ bt, const float* __restrict__ wp,
    float* __restrict__ partial) {
  __shared__ __attribute__((aligned(16))) us Ws[2][8192];  // 128h x 64k per buf (swizzled)
  __shared__ __attribute__((aligned(16))) us Ts[2][4096];  // 64t x 64k per buf (swizzled)
  __shared__ __attribute__((aligned(16))) float eL[16][132];
  __shared__ __attribute__((aligned(16))) float btL[128];
  __shared__ __attribute__((aligned(16))) float wpL[128];
  __shared__ float pp[2][64][17];
  const int tid = threadIdx.x;
  const int mh = blockIdx.x, tt = blockIdx.y;
  const int h0 = mh << 7, b = tt >> 4, t0 = (tt & 15) << 6;
  // phase 1: entity act = sum of 8 k-partials + be -> eL; bt, wp -> LDS
#pragma unroll
  for (int p = 0; p < 2; ++p) {
    int q = (p << 8) + tid;
    int er = q >> 5, ec = (q & 31) << 2;
    f32x4 s = *(const f32x4*)&be[h0 + ec];
#pragma unroll
    for (int kc = 0; kc < 8; ++kc)
      s += *(const f32x4*)&epart[(((size_t)((kc << 6) + (b << 4) + er)) << 10) + h0 + ec];
    *(f32x4*)&eL[er][ec] = s;
  }
  if (tid < 128) btL[tid] = bt[h0 + tid];
  else wpL[tid - 128] = wp[h0 + tid - 128];
  asm volatile("" ::: "memory");
  // staging geometry: chunk = 8 rows x 64k bf16 = 1KB = one gload_lds16/wave.
  // Per wave per k-tile: 4 Ws chunks (32 h-rows) + 2 Ts chunks (16 t-rows).
  const int w = tid >> 6, lane = tid & 63;
  const int lr = lane >> 3, lc = lane & 7;
  const int swz = ((lc ^ lr) << 3);  // inverse-swizzled k-element offset (const/lane)
  const us* wPs = WtT + (size_t)(h0 + (w << 5) + lr) * 1024 + swz;
  const us* tPs = tokb + (size_t)((b << 10) + t0 + (w << 4) + lr) * 1024 + swz;
  us* wD0 = &Ws[0][(w << 5) << 6];  // w*32 rows * 64 us
  us* wD1 = &Ws[1][(w << 5) << 6];
  us* tD0 = &Ts[0][(w << 4) << 6];  // w*16 rows * 64 us
  us* tD1 = &Ts[1][(w << 4) << 6];
  auto stage = [&](int kt, us* wD, us* tD) {
    const us* ws = wPs + (kt << 6);
    gload_lds16(ws,             wD);
    gload_lds16(ws + 8 * 1024,  wD + 512);
    gload_lds16(ws + 16 * 1024, wD + 1024);
    gload_lds16(ws + 24 * 1024, wD + 1536);
    const us* ts = tPs + (kt << 6);
    gload_lds16(ts,            tD);
    gload_lds16(ts + 8 * 1024, tD + 512);
  };
  // prologue: tile0 -> buf0, tile1 -> buf1 (12 outstanding, 6/tile)
  stage(0, wD0, tD0);
  stage(1, wD1, tD1);
  const int l16 = lane & 15, wm = (tid >> 7) & 1, wn = (tid >> 6) & 1, oct = lane >> 4;
  // swizzled fragment byte offsets: row*128 + ((kh*4+oct) ^ (row&7))*16
  int wfo[2][4], tfo[2][2];
#pragma unroll
  for (int kh = 0; kh < 2; ++kh)
#pragma unroll
    for (int i = 0; i < 4; ++i) {
      int row = (wm << 6) + (i << 4) + l16;
      wfo[kh][i] = (row << 7) + (((((kh << 2) + oct)) ^ (row & 7)) << 4);
    }
#pragma unroll
  for (int kh = 0; kh < 2; ++kh)
#pragma unroll
    for (int j = 0; j < 2; ++j) {
      int row = (wn << 5) + (j << 4) + l16;
      tfo[kh][j] = (row << 7) + (((((kh << 2) + oct)) ^ (row & 7)) << 4);
    }
  f32x4 acc[4][2] = {};
  for (int kt = 0; kt < 16; ++kt) {
    const char* Wb = (const char*)Ws[kt & 1];
    const char* Tb = (const char*)Ts[kt & 1];
    __builtin_amdgcn_s_waitcnt(0x0f76);  // vmcnt(6): oldest tile (6 loads) landed
    __builtin_amdgcn_s_barrier();
    asm volatile("" ::: "memory");
    short8 af[2][4], bfr[2][2];
#pragma unroll
    for (int kh = 0; kh < 2; ++kh)
#pragma unroll
      for (int i = 0; i < 4; ++i) af[kh][i] = *(const short8*)(Wb + wfo[kh][i]);
#pragma unroll
    for (int kh = 0; kh < 2; ++kh)
#pragma unroll
      for (int j = 0; j < 2; ++j) bfr[kh][j] = *(const short8*)(Tb + tfo[kh][j]);
#pragma unroll
    for (int i = 0; i < 4; ++i)
#pragma unroll
      for (int j = 0; j < 2; ++j)
        acc[i][j] = __builtin_amdgcn_mfma_f32_16x16x32_bf16(af[0][i], bfr[0][j], acc[i][j], 0, 0, 0);
#pragma unroll
    for (int i = 0; i < 4; ++i)
#pragma unroll
      for (int j = 0; j < 2; ++j)
        acc[i][j] = __builtin_amdgcn_mfma_f32_16x16x32_bf16(af[1][i], bfr[1][j], acc[i][j], 0, 0, 0);
    asm volatile("" ::: "memory");
    __builtin_amdgcn_s_barrier();
    // prefetch tile kt+2 into buf kt&1 (clamped dummy for last two iters)
    int nk = kt + 2; if (nk > 15) nk = 14;
    if (kt & 1) stage(nk, wD1, tD1); else stage(nk, wD0, tD0);
  }
  // ---- fused epilogue: per e, p[t] = sum_h relu(acc + bt + e) * Wp ----
  f32x4 btq[4], wpq[4];
#pragma unroll
  for (int i = 0; i < 4; ++i) {
    int hb = (wm << 6) + (i << 4) + (oct << 2);
    btq[i] = *(const f32x4*)&btL[hb];
    wpq[i] = *(const f32x4*)&wpL[hb];
  }
#pragma unroll
  for (int i = 0; i < 4; ++i)
#pragma unroll
    for (int j = 0; j < 2; ++j) acc[i][j] += btq[i];
#pragma unroll
  for (int e = 0; e < 16; ++e) {
    f32x4 ev[4];
#pragma unroll
    for (int i = 0; i < 4; ++i)
      ev[i] = *(const f32x4*)&eL[e][(wm << 6) + (i << 4) + (oct << 2)];
    float pj[2] = {0.f, 0.f};
#pragma unroll
    for (int j = 0; j < 2; ++j)
#pragma unroll
      for (int i = 0; i < 4; ++i)
#pragma unroll
        for (int r = 0; r < 4; ++r)
          pj[j] = fmaf(fmaxf(acc[i][j][r] + ev[i][r], 0.f), wpq[i][r], pj[j]);
#pragma unroll
    for (int j = 0; j < 2; ++j) {
      pj[j] += __shfl_xor(pj[j], 16, 64);
      pj[j] += __shfl_xor(pj[j], 32, 64);
    }
    if (oct == 0) {
#pragma unroll
      for (int j = 0; j < 2; ++j) pp[wm][(wn << 5) + (j << 4) + l16][e] = pj[j];
    }
  }
  __syncthreads();
#pragma unroll
  for (int q = 0; q < 4; ++q) {
    int flat = (q << 8) + tid;          // 0..1023 = e*64 + tl
    int e = flat >> 6, tl = flat & 63;
    float v = pp[0][tl][e] + pp[1][tl][e];
    partial[((size_t)mh << 16) + (size_t)((((b << 4) + e) << 10) + t0 + tl)] = v;
  }
}

// ---- finalize: sum 8 h-tile partials + bp, mask, sigmoid ----
__global__ __launch_bounds__(256) void finalize_kernel(
    const float* __restrict__ partial, const float* __restrict__ bp,
    const int* __restrict__ mask, float* __restrict__ out) {
  int idx = blockIdx.x * 256 + threadIdx.x;  // (b*16+e)*1024 + t
  float s = 0.f;
#pragma unroll
  for (int mh = 0; mh < 8; ++mh) s += partial[((size_t)mh << 16) + idx];
  float cls = s + bp[0];
  int b = idx >> 14, t = idx & 1023;
  if (mask[(b << 10) + t] == 0) cls = -10000.0f;
  float p = 1.0f / (1.0f + __expf(-cls));
  out[idx] = cls;
  out[65536 + idx] = p;
}

extern "C" void kernel_launch(void* const* d_in, const int* in_sizes, int n_in,
                              void* d_out, int out_size, void* d_ws, size_t ws_size,
                              hipStream_t stream) {
  const float* token = (const float*)d_in[0];
  const float* entity = (const float*)d_in[1];
  const int* mask = (const int*)d_in[2];
  const float* Wt = (const float*)d_in[3];
  const float* bt = (const float*)d_in[4];
  const float* We = (const float*)d_in[5];
  const float* be = (const float*)d_in[6];
  const float* Wp = (const float*)d_in[7];
  const float* bp = (const float*)d_in[8];
  float* out = (float*)d_out;

  char* ws = (char*)d_ws;
  us* tokb = (us*)ws;                                   // 8 MB
  us* WtT = tokb + (size_t)4096 * 1024;                 // 2 MB
  float* epart = (float*)(WtT + (size_t)1024 * 1024);   // 2 MB [8][64][1024]
  float* partial = epart + (size_t)8 * 64 * 1024;       // 2 MB [8][4*16*1024]

  prep_kernel<<<4608, 256, 0, stream>>>(token, tokb, Wt, WtT, entity, We, epart);
  main_kernel<<<dim3(8, 64), 256, 0, stream>>>(tokb, WtT, epart, be, bt, Wp, partial);
  finalize_kernel<<<256, 256, 0, stream>>>(partial, bp, mask, out);
}